// Round 9
// baseline (35.741 us; speedup 1.0000x reference)
//
#include <hip/hip_runtime.h>
#include <hip/hip_bf16.h>

// Siren fused, 32x32x16 MFMA, zero-LDS, double sigma-cancellation.
// R9: (1) launch_bounds (256,6) — 6 waves/EU for latency hiding (the kernel is
// chain-latency-bound at 4 waves); (2) hoisted shared zero C-vector (MFMA D!=C
// is legal, kills ~96 v_movs/wave); (3) w2v loaded at point of use (frees 16
// VGPRs during the main phase); (4) both x loads hoisted to kernel top.

typedef short short8 __attribute__((ext_vector_type(8)));
typedef float f32x16 __attribute__((ext_vector_type(16)));

#define THREADS 256
#define INV2PI 0.15915494309189535f

__device__ __forceinline__ unsigned packbf(float lo, float hi) {
    union { __hip_bfloat162 h; unsigned u; } v;
    v.h = __float22bfloat162_rn(make_float2(lo, hi));
    return v.u;
}

// ---- bake per-lane A fragments (W^T scaled by 1/2pi), 32x32x16 shape ----
// ws (uint4): [0..191]   A0 frags, t=0..2 : elem e of lane(h,c) = W0[h*24+8t+e][c]/2pi
//             [192..319] A1 frags, t=0..1 : elem e = W1[(e&3)+8*(e>>2)+4h+16t][c]/2pi
//             [320..575] W2 per-lane 4x float4: w2v[i] = W2[8i+4h .. +3]
__global__ void build_frags(const float* __restrict__ W0,
                            const float* __restrict__ W1,
                            const float* __restrict__ W2,
                            uint4* __restrict__ ws) {
    int l = threadIdx.x;
    if (l >= 64) return;
    int h = l >> 5, c = l & 31;

#pragma unroll
    for (int t = 0; t < 3; ++t) {
        float ev[8];
#pragma unroll
        for (int e = 0; e < 8; ++e) ev[e] = W0[(h * 24 + 8 * t + e) * 32 + c] * INV2PI;
        ws[t * 64 + l] = make_uint4(packbf(ev[0], ev[1]), packbf(ev[2], ev[3]),
                                    packbf(ev[4], ev[5]), packbf(ev[6], ev[7]));
    }
#pragma unroll
    for (int t = 0; t < 2; ++t) {
        float ev[8];
#pragma unroll
        for (int e = 0; e < 8; ++e) {
            int k = (e & 3) + 8 * (e >> 2) + 4 * h + 16 * t;
            ev[e] = W1[k * 32 + c] * INV2PI;
        }
        ws[(3 + t) * 64 + l] = make_uint4(packbf(ev[0], ev[1]), packbf(ev[2], ev[3]),
                                          packbf(ev[4], ev[5]), packbf(ev[6], ev[7]));
    }
    float4* w2v = (float4*)(ws + 320);
#pragma unroll
    for (int i = 0; i < 4; ++i)
        w2v[l * 4 + i] = make_float4(W2[8 * i + 4 * h + 0], W2[8 * i + 4 * h + 1],
                                     W2[8 * i + 4 * h + 2], W2[8 * i + 4 * h + 3]);
}

__global__ __launch_bounds__(THREADS, 6) void siren_mfma_kernel(
    const float* __restrict__ xf,     // [N][2] flat
    const uint4* __restrict__ wf,
    float* __restrict__ out,
    int n)
{
    const int lane = threadIdx.x & 63;
    const int wid = threadIdx.x >> 6;
    const int q = lane & 31, h = lane >> 5;
    const int p0 = blockIdx.x * THREADS + wid * 64;
    if (p0 >= n) return;

    // ---- both x loads in flight immediately ----
    const float xd0 = xf[(p0 + q) * 2 + h];
    const float xd1 = xf[(p0 + 32 + q) * 2 + h];

    union U { uint4 u; short8 v; };
    short8 a0[3], a1[2];
#pragma unroll
    for (int t = 0; t < 3; ++t) { U tt; tt.u = wf[t * 64 + lane]; a0[t] = tt.v; }
#pragma unroll
    for (int t = 0; t < 2; ++t) { U tt; tt.u = wf[(3 + t) * 64 + lane]; a1[t] = tt.v; }

    // shared zero accumulator input (MFMA C != D: no copies needed)
    f32x16 zacc;
#pragma unroll
    for (int i = 0; i < 16; ++i) zacc[i] = 0.0f;

    float vres[2];

#pragma unroll
    for (int b = 0; b < 2; ++b) {
        // ---- enc: dim h of point (p0 + 32b + q), 12 sin + 12 cos ----
        const float xd = b ? xd1 : xd0;
        float sv[12], cv[12];
        {
            float r0 = __builtin_amdgcn_fractf(xd * 0.5f);     // j=0 seed
            sv[0] = __builtin_amdgcn_sinf(r0);
            cv[0] = __builtin_amdgcn_cosf(r0);
#pragma unroll
            for (int j = 1; j < 6; ++j) {
                float t = sv[j - 1] + sv[j - 1];
                sv[j] = t * cv[j - 1];
                cv[j] = fmaf(-t, sv[j - 1], 1.0f);
            }
            float r1 = __builtin_amdgcn_fractf(xd * 32.0f);    // j=6 seed
            sv[6] = __builtin_amdgcn_sinf(r1);
            cv[6] = __builtin_amdgcn_cosf(r1);
#pragma unroll
            for (int j = 7; j < 12; ++j) {
                float t = sv[j - 1] + sv[j - 1];
                sv[j] = t * cv[j - 1];
                cv[j] = fmaf(-t, sv[j - 1], 1.0f);
            }
        }

        // ---- B0 fragments: elem(t,e) = enc idx 8t+e (idx<12: sin, else cos) ----
        union { unsigned u[4]; short8 v; } bf0, bf1, bf2;
        bf0.u[0] = packbf(sv[0], sv[1]);  bf0.u[1] = packbf(sv[2], sv[3]);
        bf0.u[2] = packbf(sv[4], sv[5]);  bf0.u[3] = packbf(sv[6], sv[7]);
        bf1.u[0] = packbf(sv[8], sv[9]);  bf1.u[1] = packbf(sv[10], sv[11]);
        bf1.u[2] = packbf(cv[0], cv[1]);  bf1.u[3] = packbf(cv[2], cv[3]);
        bf2.u[0] = packbf(cv[4], cv[5]);  bf2.u[1] = packbf(cv[6], cv[7]);
        bf2.u[2] = packbf(cv[8], cv[9]);  bf2.u[3] = packbf(cv[10], cv[11]);

        // ---- layer 0: 3 MFMAs, C[32 chan][32 pt], acc in revolutions ----
        f32x16 acc;
        acc = __builtin_amdgcn_mfma_f32_32x32x16_bf16(a0[0], bf0.v, zacc, 0, 0, 0);
        acc = __builtin_amdgcn_mfma_f32_32x32x16_bf16(a0[1], bf1.v, acc, 0, 0, 0);
        acc = __builtin_amdgcn_mfma_f32_32x32x16_bf16(a0[2], bf2.v, acc, 0, 0, 0);

        // ---- act (bare v_sin) -> B1 fragments in-lane ----
        union { unsigned u[4]; short8 v; } b1a, b1b;
#pragma unroll
        for (int i = 0; i < 4; ++i)
            b1a.u[i] = packbf(__builtin_amdgcn_sinf(acc[2 * i]),
                              __builtin_amdgcn_sinf(acc[2 * i + 1]));
#pragma unroll
        for (int i = 0; i < 4; ++i)
            b1b.u[i] = packbf(__builtin_amdgcn_sinf(acc[8 + 2 * i]),
                              __builtin_amdgcn_sinf(acc[8 + 2 * i + 1]));

        // ---- layer 1: 2 MFMAs, acc1 in revolutions ----
        f32x16 acc1;
        acc1 = __builtin_amdgcn_mfma_f32_32x32x16_bf16(a1[0], b1a.v, zacc, 0, 0, 0);
        acc1 = __builtin_amdgcn_mfma_f32_32x32x16_bf16(a1[1], b1b.v, acc1, 0, 0, 0);

        // ---- W2 fragment loaded at point of use (hides under the sin burst) ----
        float4 w2v[4];
#pragma unroll
        for (int i = 0; i < 4; ++i) w2v[i] = ((const float4*)(wf + 320))[lane * 4 + i];

        // ---- act + W2 dot: reg r -> chan (r&3)+8*(r>>2)+4h -> w2v[r>>2][r&3] ----
        float s0, s1, s2, s3;
        s0 = __builtin_amdgcn_sinf(acc1[0]) * w2v[0].x;
        s0 = fmaf(__builtin_amdgcn_sinf(acc1[1]), w2v[0].y, s0);
        s0 = fmaf(__builtin_amdgcn_sinf(acc1[2]), w2v[0].z, s0);
        s0 = fmaf(__builtin_amdgcn_sinf(acc1[3]), w2v[0].w, s0);
        s1 = __builtin_amdgcn_sinf(acc1[4]) * w2v[1].x;
        s1 = fmaf(__builtin_amdgcn_sinf(acc1[5]), w2v[1].y, s1);
        s1 = fmaf(__builtin_amdgcn_sinf(acc1[6]), w2v[1].z, s1);
        s1 = fmaf(__builtin_amdgcn_sinf(acc1[7]), w2v[1].w, s1);
        s2 = __builtin_amdgcn_sinf(acc1[8]) * w2v[2].x;
        s2 = fmaf(__builtin_amdgcn_sinf(acc1[9]), w2v[2].y, s2);
        s2 = fmaf(__builtin_amdgcn_sinf(acc1[10]), w2v[2].z, s2);
        s2 = fmaf(__builtin_amdgcn_sinf(acc1[11]), w2v[2].w, s2);
        s3 = __builtin_amdgcn_sinf(acc1[12]) * w2v[3].x;
        s3 = fmaf(__builtin_amdgcn_sinf(acc1[13]), w2v[3].y, s3);
        s3 = fmaf(__builtin_amdgcn_sinf(acc1[14]), w2v[3].z, s3);
        s3 = fmaf(__builtin_amdgcn_sinf(acc1[15]), w2v[3].w, s3);
        vres[b] = (s0 + s1) + (s2 + s3);
    }

    // ---- cross-half reduce (2 lanes per point) + coalesced store ----
    vres[0] += __shfl_xor(vres[0], 32, 64);
    vres[1] += __shfl_xor(vres[1], 32, 64);
    out[p0 + lane] = h ? vres[1] : vres[0];
}

extern "C" void kernel_launch(void* const* d_in, const int* in_sizes, int n_in,
                              void* d_out, int out_size, void* d_ws, size_t ws_size,
                              hipStream_t stream) {
    const float* xf = (const float*)d_in[0];
    const float* W0 = (const float*)d_in[1];
    const float* W1 = (const float*)d_in[2];
    const float* W2 = (const float*)d_in[3];
    float* out = (float*)d_out;
    uint4* ws = (uint4*)d_ws;

    const int n = in_sizes[0] / 2;
    build_frags<<<1, 64, 0, stream>>>(W0, W1, W2, ws);
    const int blocks = (n + THREADS - 1) / THREADS;
    siren_mfma_kernel<<<blocks, THREADS, 0, stream>>>(xf, ws, out, n);
}